// Round 1
// baseline (1403.951 us; speedup 1.0000x reference)
//
#include <hip/hip_runtime.h>

#define TOKENS 8192
#define D_IN   4096
#define FEATS  16384

typedef __attribute__((ext_vector_type(8))) short short8;
typedef __attribute__((ext_vector_type(4))) float f32x4;

__device__ __forceinline__ unsigned short f2bf(float f) {
  unsigned int u = __float_as_uint(f);
  u = (u + 0x7fffu + ((u >> 16) & 1u)) >> 16;  // RNE
  return (unsigned short)u;
}

__device__ __forceinline__ void gload_lds16(const void* g, void* l) {
  __builtin_amdgcn_global_load_lds(
      (const __attribute__((address_space(1))) void*)g,
      (__attribute__((address_space(3))) void*)l, 16, 0, 0);
}

// ---------------- pre-pass A: x fp32 -> bf16 ----------------
__global__ __launch_bounds__(256) void cvt_x_kernel(const float* __restrict__ x,
                                                    unsigned short* __restrict__ xb) {
  long i = ((long)blockIdx.x * 256 + threadIdx.x) * 8;
  const float4* p = (const float4*)(x + i);
  float4 a = p[0], b = p[1];
  short8 o;
  o[0] = (short)f2bf(a.x); o[1] = (short)f2bf(a.y);
  o[2] = (short)f2bf(a.z); o[3] = (short)f2bf(a.w);
  o[4] = (short)f2bf(b.x); o[5] = (short)f2bf(b.y);
  o[6] = (short)f2bf(b.z); o[7] = (short)f2bf(b.w);
  *(short8*)(xb + i) = o;
}

// ---------------- pre-pass B: kernel int32 [K][N] -> bf16 Wt [N][K] ----------------
// values in [0,8) are exact in bf16; scale is applied in the GEMM epilogue.
__global__ __launch_bounds__(256) void wtrans_kernel(const int* __restrict__ kq,
                                                     unsigned short* __restrict__ wt) {
  __shared__ unsigned short tile[32][33];
  const int n0 = blockIdx.x * 32, k0 = blockIdx.y * 32;
  const int tx = threadIdx.x, ty = threadIdx.y;  // 32 x 8
#pragma unroll
  for (int r = 0; r < 4; r++) {
    int kl = ty + r * 8;
    int v = kq[(long)(k0 + kl) * FEATS + n0 + tx];
    tile[kl][tx] = f2bf((float)v);
  }
  __syncthreads();
#pragma unroll
  for (int r = 0; r < 4; r++) {
    int nl = ty + r * 8;
    wt[(long)(n0 + nl) * D_IN + k0 + tx] = tile[tx][nl];
  }
}

// ---------------- main GEMM: m97 structure, 128x128 tile, BK=32 ----------------
__global__ __launch_bounds__(256) void gemm_kernel(
    const unsigned short* __restrict__ Xb,   // [M][K] bf16
    const unsigned short* __restrict__ Wt,   // [N][K] bf16
    const float* __restrict__ scale,         // [N]
    const float* __restrict__ bias,          // [N]
    float* __restrict__ C) {                 // [M][N] fp32
  __shared__ __attribute__((aligned(16))) unsigned short As[128 * 32];
  __shared__ __attribute__((aligned(16))) unsigned short Bs[128 * 32];
  const int tid = threadIdx.x;
  const int lane = tid & 63, wid = tid >> 6;
  const int m0 = blockIdx.y * 128, n0 = blockIdx.x * 128;
  const int wr = wid >> 1, wc = wid & 1;     // 2x2 waves of 64x64
  const int rl = lane & 15, kq = lane >> 4;

  f32x4 acc[4][4] = {};

  // staging chunks: 512 x 16B per tile; chunk c -> row c>>2, k-offset (c&3)*8 elems
  const int c0 = tid, c1 = tid + 256;
  const int r0 = c0 >> 2, o0 = (c0 & 3) * 8;
  const int r1 = c1 >> 2, o1 = (c1 & 3) * 8;
  const long aOff0 = (long)(m0 + r0) * D_IN + o0;
  const long aOff1 = (long)(m0 + r1) * D_IN + o1;
  const long bOff0 = (long)(n0 + r0) * D_IN + o0;
  const long bOff1 = (long)(n0 + r1) * D_IN + o1;
  char* ldsA0 = (char*)As + (wid * 64) * 16;          // wave-uniform LDS dests
  char* ldsA1 = (char*)As + (256 + wid * 64) * 16;
  char* ldsB0 = (char*)Bs + (wid * 64) * 16;
  char* ldsB1 = (char*)Bs + (256 + wid * 64) * 16;

  for (int k0 = 0; k0 < D_IN; k0 += 32) {
    gload_lds16(Xb + aOff0 + k0, ldsA0);
    gload_lds16(Xb + aOff1 + k0, ldsA1);
    gload_lds16(Wt + bOff0 + k0, ldsB0);
    gload_lds16(Wt + bOff1 + k0, ldsB1);
    __syncthreads();

    short8 af[4], bfr[4];
#pragma unroll
    for (int i = 0; i < 4; i++) {
      af[i]  = *(const short8*)(As + (wr * 64 + i * 16 + rl) * 32 + kq * 8);
      bfr[i] = *(const short8*)(Bs + (wc * 64 + i * 16 + rl) * 32 + kq * 8);
    }
#pragma unroll
    for (int i = 0; i < 4; i++)
#pragma unroll
      for (int j = 0; j < 4; j++)
        acc[i][j] = __builtin_amdgcn_mfma_f32_16x16x32_bf16(af[i], bfr[j], acc[i][j], 0, 0, 0);
    __syncthreads();
  }

  // epilogue: y = acc * (1/scale[col]) + bias[col]
#pragma unroll
  for (int j = 0; j < 4; j++) {
    const int col = n0 + wc * 64 + j * 16 + rl;
    const float rs = 1.0f / scale[col];
    const float bv = bias[col];
#pragma unroll
    for (int i = 0; i < 4; i++) {
      const int row0 = m0 + wr * 64 + i * 16 + kq * 4;
#pragma unroll
      for (int r = 0; r < 4; r++) {
        C[(long)(row0 + r) * FEATS + col] = acc[i][j][r] * rs + bv;
      }
    }
  }
}

// ---------------- fallback (ws too small): naive fp32 tiled GEMM ----------------
__global__ void naive_kernel(const float* __restrict__ x, const int* __restrict__ kq,
                             const float* __restrict__ scale, const float* __restrict__ bias,
                             float* __restrict__ out) {
  __shared__ float xa[16][16];
  __shared__ float wb[16][17];
  const int n = blockIdx.x * 16 + threadIdx.x;
  const int m = blockIdx.y * 16 + threadIdx.y;
  float accv = 0.f;
  for (int k0 = 0; k0 < D_IN; k0 += 16) {
    xa[threadIdx.y][threadIdx.x] = x[(long)m * D_IN + k0 + threadIdx.x];
    wb[threadIdx.y][threadIdx.x] = (float)kq[(long)(k0 + threadIdx.y) * FEATS + n];
    __syncthreads();
#pragma unroll
    for (int kk = 0; kk < 16; kk++) accv += xa[threadIdx.y][kk] * wb[kk][threadIdx.x];
    __syncthreads();
  }
  out[(long)m * FEATS + n] = accv * (1.0f / scale[n]) + bias[n];
}

extern "C" void kernel_launch(void* const* d_in, const int* in_sizes, int n_in,
                              void* d_out, int out_size, void* d_ws, size_t ws_size,
                              hipStream_t stream) {
  const float* x     = (const float*)d_in[0];
  const int*   kq    = (const int*)d_in[1];
  const float* scale = (const float*)d_in[2];
  const float* bias  = (const float*)d_in[3];
  float* out = (float*)d_out;

  const size_t need = ((size_t)TOKENS * D_IN + (size_t)FEATS * D_IN) * 2;
  if (ws_size < need) {
    naive_kernel<<<dim3(FEATS / 16, TOKENS / 16), dim3(16, 16), 0, stream>>>(
        x, kq, scale, bias, out);
    return;
  }

  unsigned short* Xb = (unsigned short*)d_ws;
  unsigned short* Wt = Xb + (size_t)TOKENS * D_IN;

  cvt_x_kernel<<<(TOKENS * (long)D_IN) / (256 * 8), 256, 0, stream>>>(x, Xb);
  wtrans_kernel<<<dim3(FEATS / 32, D_IN / 32), dim3(32, 8), 0, stream>>>(kq, Wt);
  gemm_kernel<<<dim3(FEATS / 128, TOKENS / 128), 256, 0, stream>>>(Xb, Wt, scale, bias, out);
}

// Round 2
// 1086.133 us; speedup vs baseline: 1.2926x; 1.2926x over previous
//
#include <hip/hip_runtime.h>

#define TOKENS 8192
#define D_IN   4096
#define FEATS  16384
#define NT     (D_IN / 64)   // 64 K-tiles of 64
#define NIT    (NT / 2)      // 32 iterations, 2 K-tiles each

typedef __attribute__((ext_vector_type(8))) short short8;
typedef __attribute__((ext_vector_type(4))) float f32x4;

__device__ __forceinline__ unsigned short f2bf(float f) {
  unsigned int u = __float_as_uint(f);
  u = (u + 0x7fffu + ((u >> 16) & 1u)) >> 16;  // RNE
  return (unsigned short)u;
}

__device__ __forceinline__ void gload_lds16(const void* g, void* l) {
  __builtin_amdgcn_global_load_lds(
      (const __attribute__((address_space(1))) void*)g,
      (__attribute__((address_space(3))) void*)l, 16, 0, 0);
}

// ---------------- pre-pass A: x fp32 -> bf16 ----------------
__global__ __launch_bounds__(256) void cvt_x_kernel(const float* __restrict__ x,
                                                    unsigned short* __restrict__ xb) {
  long i = ((long)blockIdx.x * 256 + threadIdx.x) * 8;
  const float4* p = (const float4*)(x + i);
  float4 a = p[0], b = p[1];
  short8 o;
  o[0] = (short)f2bf(a.x); o[1] = (short)f2bf(a.y);
  o[2] = (short)f2bf(a.z); o[3] = (short)f2bf(a.w);
  o[4] = (short)f2bf(b.x); o[5] = (short)f2bf(b.y);
  o[6] = (short)f2bf(b.z); o[7] = (short)f2bf(b.w);
  *(short8*)(xb + i) = o;
}

// ---------------- pre-pass B: kernel int32 [K][N] -> bf16 Wt [N][K] ----------------
__global__ __launch_bounds__(256) void wtrans_kernel(const int* __restrict__ kq,
                                                     unsigned short* __restrict__ wt) {
  __shared__ unsigned short tile[32][33];
  const int n0 = blockIdx.x * 32, k0 = blockIdx.y * 32;
  const int tx = threadIdx.x, ty = threadIdx.y;  // 32 x 8
#pragma unroll
  for (int r = 0; r < 4; r++) {
    int kl = ty + r * 8;
    int v = kq[(long)(k0 + kl) * FEATS + n0 + tx];
    tile[kl][tx] = f2bf((float)v);
  }
  __syncthreads();
#pragma unroll
  for (int r = 0; r < 4; r++) {
    int nl = ty + r * 8;
    wt[(long)(n0 + nl) * D_IN + k0 + tx] = tile[tx][nl];
  }
}

// ---------------- main GEMM: 256x256 tile, BK=64, 8-phase schedule ----------------
#define BAR        __builtin_amdgcn_s_barrier()
#define WAIT_LGKM  asm volatile("s_waitcnt lgkmcnt(0)" ::: "memory")
#define VMCNT6     asm volatile("s_waitcnt vmcnt(6)" ::: "memory")
#define VMCNT0     asm volatile("s_waitcnt vmcnt(0)" ::: "memory")
#define PRIO1      __builtin_amdgcn_s_setprio(1)
#define PRIO0      __builtin_amdgcn_s_setprio(0)

// stage one 64-row quarter (8 KiB) of A or B for K-tile KT into buf B_
#define STAGE_A(B_, R0, KT) do { if ((KT) < NT) \
  gload_lds16(Xb + (m0 + (R0) + sr) * (long)D_IN + (long)(KT) * 64 + sgx, \
              (char*)&lds[B_][0][0] + (R0) * 128 + wid * 1024); } while (0)
#define STAGE_B(B_, R0, KT) do { if ((KT) < NT) \
  gload_lds16(Wt + (n0 + (R0) + sr) * (long)D_IN + (long)(KT) * 64 + sgx, \
              (char*)&lds[B_][1][0] + (R0) * 128 + wid * 1024); } while (0)

// swizzled fragment reads (ks=0,1 packed per call)
#define LDA1(B_, I) do { \
  const char* _p = (const char*)&lds[B_][0][0] + (wr * 128 + (I) * 16 + rl) * 128; \
  aF[(I) & 3][0] = *(const short8*)(_p + koff0); \
  aF[(I) & 3][1] = *(const short8*)(_p + koff1); } while (0)
#define LDA4(B_, H) do { LDA1(B_, (H)*4+0); LDA1(B_, (H)*4+1); LDA1(B_, (H)*4+2); LDA1(B_, (H)*4+3); } while (0)
#define LDB1(B_, J) do { \
  const char* _p = (const char*)&lds[B_][1][0] + (wc * 64 + (J) * 16 + rl) * 128; \
  bF[J][0] = *(const short8*)(_p + koff0); \
  bF[J][1] = *(const short8*)(_p + koff1); } while (0)
#define LDB4(B_) do { LDB1(B_, 0); LDB1(B_, 1); LDB1(B_, 2); LDB1(B_, 3); } while (0)

#define MM1(I, J, KS) \
  acc[I][J] = __builtin_amdgcn_mfma_f32_16x16x32_bf16(aF[(I) & 3][KS], bF[J][KS], acc[I][J], 0, 0, 0)
#define MM16(H, JH) do { \
  MM1((H)*4+0,(JH)*2+0,0); MM1((H)*4+0,(JH)*2+0,1); \
  MM1((H)*4+0,(JH)*2+1,0); MM1((H)*4+0,(JH)*2+1,1); \
  MM1((H)*4+1,(JH)*2+0,0); MM1((H)*4+1,(JH)*2+0,1); \
  MM1((H)*4+1,(JH)*2+1,0); MM1((H)*4+1,(JH)*2+1,1); \
  MM1((H)*4+2,(JH)*2+0,0); MM1((H)*4+2,(JH)*2+0,1); \
  MM1((H)*4+2,(JH)*2+1,0); MM1((H)*4+2,(JH)*2+1,1); \
  MM1((H)*4+3,(JH)*2+0,0); MM1((H)*4+3,(JH)*2+0,1); \
  MM1((H)*4+3,(JH)*2+1,0); MM1((H)*4+3,(JH)*2+1,1); } while (0)

__global__ __launch_bounds__(512, 2) void gemm8_kernel(
    const unsigned short* __restrict__ Xb,   // [M][K] bf16
    const unsigned short* __restrict__ Wt,   // [N][K] bf16
    const float* __restrict__ scale,
    const float* __restrict__ bias,
    float* __restrict__ C) {
  // lds[buf][0]=A tile [256][64], lds[buf][1]=B tile [256][64]; 128 KiB total
  __shared__ __attribute__((aligned(16))) unsigned short lds[2][2][256 * 64];

  const int tid = threadIdx.x;
  const int lane = tid & 63, wid = tid >> 6;
  const int wr = wid >> 2, wc = wid & 3;       // 2 x 4 wave grid, each 128x64 out
  const int rl = lane & 15, q = lane >> 4;

  // T1: bijective XCD swizzle (2048 blocks, %8 == 0)
  const int bid = blockIdx.x;
  const int swz = (bid & 7) * 256 + (bid >> 3);
  const long m0 = (long)(swz >> 6) * 256;      // 32 rows of tiles
  const long n0 = (long)(swz & 63) * 256;      // 64 cols of tiles

  // staging geometry: thread t covers row sr, k-granule sg of a 64-row quarter;
  // source granule pre-swizzled so linear LDS dest holds swizzled layout (rule 21)
  const int sr = tid >> 3;
  const int sgx = ((tid & 7) ^ (sr & 7)) * 8;  // element offset

  // read-side swizzle: byte ^= ((row&7)<<4); row&7 == rl&7 for all fragments
  const int xm = (rl & 7) << 4;
  const int koff0 = (q * 16) ^ xm;             // ks=0
  const int koff1 = (64 + q * 16) ^ xm;        // ks=1

  f32x4 acc[8][4] = {};
  short8 aF[4][2], bF[4][2];

  // ---- prologue: tile0 full (8 quarters) + tile1 B + A-q0,q2 (6 quarters) ----
  STAGE_B(0, 0, 0); STAGE_B(0, 64, 0); STAGE_B(0, 128, 0); STAGE_B(0, 192, 0);
  STAGE_A(0, 0, 0); STAGE_A(0, 64, 0); STAGE_A(0, 128, 0); STAGE_A(0, 192, 0);
  STAGE_B(1, 0, 1); STAGE_B(1, 64, 1); STAGE_B(1, 128, 1); STAGE_B(1, 192, 1);
  STAGE_A(1, 0, 1); STAGE_A(1, 128, 1);
  VMCNT6;   // tile0's 8 landed; tile1's 6 in flight
  BAR;

  for (int it = 0; it < NIT; ++it) {
    const int t1 = 2 * it + 1, t2 = 2 * it + 2, t3 = 2 * it + 3;
    // ph0: compute tile 2it quadrant (0,0); stage t1 A-q1,q3 (read at ph6)
    LDA4(0, 0); LDB4(0);
    STAGE_A(1, 64, t1); STAGE_A(1, 192, t1);
    WAIT_LGKM; PRIO1; MM16(0, 0); PRIO0;
    BAR;
    // ph1: quadrant (0,1); stage t2 B-q0,q1 (B retired at ph0)
    STAGE_B(0, 0, t2); STAGE_B(0, 64, t2);
    PRIO1; MM16(0, 1); PRIO0;
    BAR;
    // ph2: quadrant (1,0); stage t2 B-q2,q3
    LDA4(0, 1);
    STAGE_B(0, 128, t2); STAGE_B(0, 192, t2);
    WAIT_LGKM; PRIO1; MM16(1, 0); PRIO0;
    BAR;
    // ph3: quadrant (1,1); stage t2 A-q0,q2 (retired at ph0); tile-boundary wait
    STAGE_A(0, 0, t2); STAGE_A(0, 128, t2);
    PRIO1; MM16(1, 1); PRIO0;
    if (it == NIT - 1) { VMCNT0; } else { VMCNT6; }   // t1 fully landed
    BAR;
    // ph4: tile 2it+1 quadrant (0,0); stage t2 A-q1,q3 (retired at ph2)
    LDA4(1, 0); LDB4(1);
    STAGE_A(0, 64, t2); STAGE_A(0, 192, t2);
    WAIT_LGKM; PRIO1; MM16(0, 0); PRIO0;
    BAR;
    // ph5: quadrant (0,1); stage t3 B-q0,q1 (retired at ph4)
    STAGE_B(1, 0, t3); STAGE_B(1, 64, t3);
    PRIO1; MM16(0, 1); PRIO0;
    BAR;
    // ph6: quadrant (1,0); stage t3 B-q2,q3
    LDA4(1, 1);
    STAGE_B(1, 128, t3); STAGE_B(1, 192, t3);
    WAIT_LGKM; PRIO1; MM16(1, 0); PRIO0;
    BAR;
    // ph7: quadrant (1,1); stage t3 A-q0,q2 (retired at ph4); boundary wait
    STAGE_A(1, 0, t3); STAGE_A(1, 128, t3);
    PRIO1; MM16(1, 1); PRIO0;
    VMCNT6;   // t2 fully landed for next iter's ph0
    BAR;
  }

  // ---- epilogue: y = acc * (1/scale[col]) + bias[col] ----
#pragma unroll
  for (int j = 0; j < 4; j++) {
    const long col = n0 + wc * 64 + j * 16 + rl;
    const float rs = 1.0f / scale[col];
    const float bv = bias[col];
#pragma unroll
    for (int i = 0; i < 8; i++) {
      const long row0 = m0 + wr * 128 + i * 16 + q * 4;
#pragma unroll
      for (int r = 0; r < 4; r++) {
        C[(row0 + r) * (long)FEATS + col] = acc[i][j][r] * rs + bv;
      }
    }
  }
}

// ---------------- fallback (ws too small): naive fp32 tiled GEMM ----------------
__global__ void naive_kernel(const float* __restrict__ x, const int* __restrict__ kq,
                             const float* __restrict__ scale, const float* __restrict__ bias,
                             float* __restrict__ out) {
  __shared__ float xa[16][16];
  __shared__ float wb[16][17];
  const int n = blockIdx.x * 16 + threadIdx.x;
  const int m = blockIdx.y * 16 + threadIdx.y;
  float accv = 0.f;
  for (int k0 = 0; k0 < D_IN; k0 += 16) {
    xa[threadIdx.y][threadIdx.x] = x[(long)m * D_IN + k0 + threadIdx.x];
    wb[threadIdx.y][threadIdx.x] = (float)kq[(long)(k0 + threadIdx.y) * FEATS + n];
    __syncthreads();
#pragma unroll
    for (int kk = 0; kk < 16; kk++) accv += xa[threadIdx.y][kk] * wb[kk][threadIdx.x];
    __syncthreads();
  }
  out[(long)m * FEATS + n] = accv * (1.0f / scale[n]) + bias[n];
}

extern "C" void kernel_launch(void* const* d_in, const int* in_sizes, int n_in,
                              void* d_out, int out_size, void* d_ws, size_t ws_size,
                              hipStream_t stream) {
  const float* x     = (const float*)d_in[0];
  const int*   kq    = (const int*)d_in[1];
  const float* scale = (const float*)d_in[2];
  const float* bias  = (const float*)d_in[3];
  float* out = (float*)d_out;

  const size_t need = ((size_t)TOKENS * D_IN + (size_t)FEATS * D_IN) * 2;
  if (ws_size < need) {
    naive_kernel<<<dim3(FEATS / 16, TOKENS / 16), dim3(16, 16), 0, stream>>>(
        x, kq, scale, bias, out);
    return;
  }

  unsigned short* Xb = (unsigned short*)d_ws;
  unsigned short* Wt = Xb + (size_t)TOKENS * D_IN;

  cvt_x_kernel<<<(TOKENS * (long)D_IN) / (256 * 8), 256, 0, stream>>>(x, Xb);
  wtrans_kernel<<<dim3(FEATS / 32, D_IN / 32), dim3(32, 8), 0, stream>>>(kq, Wt);
  gemm8_kernel<<<dim3((TOKENS / 256) * (FEATS / 256)), 512, 0, stream>>>(
      Xb, Wt, scale, bias, out);
}

// Round 3
// 652.984 us; speedup vs baseline: 2.1501x; 1.6633x over previous
//
#include <hip/hip_runtime.h>

#define TOKENS 8192
#define D_IN   4096
#define FEATS  16384
#define NT     (D_IN / 128)  // 32 K-tiles of 128 (i8)
#define NIT    (NT / 2)      // 16 iterations, 2 K-tiles each

typedef __attribute__((ext_vector_type(4))) int   i4v;
typedef __attribute__((ext_vector_type(4))) float f32x4;

__device__ __forceinline__ void gload_lds16(const void* g, void* l) {
  __builtin_amdgcn_global_load_lds(
      (const __attribute__((address_space(1))) void*)g,
      (__attribute__((address_space(3))) void*)l, 16, 0, 0);
}

// ---------------- pre-pass A: x fp32 -> int8 with per-row scale ----------------
__device__ __forceinline__ int pack4(float4 f, float inv) {
  int a = __float2int_rn(f.x * inv), b = __float2int_rn(f.y * inv),
      c = __float2int_rn(f.z * inv), d = __float2int_rn(f.w * inv);
  return (a & 0xff) | ((b & 0xff) << 8) | ((c & 0xff) << 16) | ((d & 0xff) << 24);
}

__global__ __launch_bounds__(256) void quant_x_kernel(const float* __restrict__ x,
                                                      signed char* __restrict__ xq,
                                                      float* __restrict__ xs) {
  const int row = blockIdx.x, t = threadIdx.x;
  const float* xr = x + (long)row * D_IN;
  float4 v0 = *(const float4*)(xr + t * 16 + 0);
  float4 v1 = *(const float4*)(xr + t * 16 + 4);
  float4 v2 = *(const float4*)(xr + t * 16 + 8);
  float4 v3 = *(const float4*)(xr + t * 16 + 12);
  float m = 0.f;
  m = fmaxf(m, fmaxf(fmaxf(fabsf(v0.x), fabsf(v0.y)), fmaxf(fabsf(v0.z), fabsf(v0.w))));
  m = fmaxf(m, fmaxf(fmaxf(fabsf(v1.x), fabsf(v1.y)), fmaxf(fabsf(v1.z), fabsf(v1.w))));
  m = fmaxf(m, fmaxf(fmaxf(fabsf(v2.x), fabsf(v2.y)), fmaxf(fabsf(v2.z), fabsf(v2.w))));
  m = fmaxf(m, fmaxf(fmaxf(fabsf(v3.x), fabsf(v3.y)), fmaxf(fabsf(v3.z), fabsf(v3.w))));
#pragma unroll
  for (int off = 32; off >= 1; off >>= 1) m = fmaxf(m, __shfl_xor(m, off));
  __shared__ float wm[4];
  if ((t & 63) == 0) wm[t >> 6] = m;
  __syncthreads();
  m = fmaxf(fmaxf(wm[0], wm[1]), fmaxf(wm[2], wm[3]));
  m = fmaxf(m, 1e-20f);
  const float inv = 127.f / m;
  if (t == 0) xs[row] = m / 127.f;
  int4 o;
  o.x = pack4(v0, inv); o.y = pack4(v1, inv);
  o.z = pack4(v2, inv); o.w = pack4(v3, inv);
  *(int4*)(xq + (long)row * D_IN + t * 16) = o;
}

// ---------------- pre-pass B: kernel int32 [K][N] -> int8 Wq [N][K] ----------------
__global__ __launch_bounds__(256) void wtrans8_kernel(const int* __restrict__ kq,
                                                      signed char* __restrict__ wt) {
  __shared__ signed char tile[64][68];
  const int n0 = blockIdx.x * 64, k0 = blockIdx.y * 64;
  const int t = threadIdx.x;
  const int kr = t >> 4, nc = (t & 15) * 4;
#pragma unroll
  for (int p = 0; p < 4; p++) {
    int4 v = *(const int4*)(kq + (long)(k0 + kr + 16 * p) * FEATS + n0 + nc);
    tile[kr + 16 * p][nc + 0] = (signed char)v.x;
    tile[kr + 16 * p][nc + 1] = (signed char)v.y;
    tile[kr + 16 * p][nc + 2] = (signed char)v.z;
    tile[kr + 16 * p][nc + 3] = (signed char)v.w;
  }
  __syncthreads();
  const int nr = t >> 4, kc = (t & 15) * 4;
#pragma unroll
  for (int p = 0; p < 4; p++) {
    int n = nr + 16 * p;
    int o = (tile[kc + 0][n] & 0xff) | ((tile[kc + 1][n] & 0xff) << 8) |
            ((tile[kc + 2][n] & 0xff) << 16) | ((tile[kc + 3][n] & 0xff) << 24);
    *(int*)(wt + (long)(n0 + n) * D_IN + k0 + kc) = o;
  }
}

// ---------------- main GEMM: 256x256 tile, BK=128 i8, 8-phase schedule ----------------
#define BAR        __builtin_amdgcn_s_barrier()
#define WAIT_LGKM  asm volatile("s_waitcnt lgkmcnt(0)" ::: "memory")
#define VMCNT6     asm volatile("s_waitcnt vmcnt(6)" ::: "memory")
#define VMCNT0     asm volatile("s_waitcnt vmcnt(0)" ::: "memory")
#define PRIO1      __builtin_amdgcn_s_setprio(1)
#define PRIO0      __builtin_amdgcn_s_setprio(0)

// stage one 64-row quarter (8 KiB) of A or B for K-tile KT into buf B_
#define STAGE_A(B_, R0, KT) do { if ((KT) < NT) \
  gload_lds16(Xq + (m0 + (R0) + sr) * (long)D_IN + (long)(KT) * 128 + sgb, \
              (char*)&lds[B_][0][0] + (R0) * 128 + wid * 1024); } while (0)
#define STAGE_B(B_, R0, KT) do { if ((KT) < NT) \
  gload_lds16(Wq + (n0 + (R0) + sr) * (long)D_IN + (long)(KT) * 128 + sgb, \
              (char*)&lds[B_][1][0] + (R0) * 128 + wid * 1024); } while (0)

// swizzled fragment reads (ks=0,1 packed per call)
#define LDA1(B_, I) do { \
  const char* _p = (const char*)&lds[B_][0][0] + (wr * 128 + (I) * 16 + rl) * 128; \
  aF[(I) & 3][0] = *(const i4v*)(_p + koff0); \
  aF[(I) & 3][1] = *(const i4v*)(_p + koff1); } while (0)
#define LDA4(B_, H) do { LDA1(B_, (H)*4+0); LDA1(B_, (H)*4+1); LDA1(B_, (H)*4+2); LDA1(B_, (H)*4+3); } while (0)
#define LDB1(B_, J) do { \
  const char* _p = (const char*)&lds[B_][1][0] + (wc * 64 + (J) * 16 + rl) * 128; \
  bF[J][0] = *(const i4v*)(_p + koff0); \
  bF[J][1] = *(const i4v*)(_p + koff1); } while (0)
#define LDB4(B_) do { LDB1(B_, 0); LDB1(B_, 1); LDB1(B_, 2); LDB1(B_, 3); } while (0)

#define MM1(I, J, KS) \
  acc[I][J] = __builtin_amdgcn_mfma_i32_16x16x64_i8(aF[(I) & 3][KS], bF[J][KS], acc[I][J], 0, 0, 0)
#define MM16(H, JH) do { \
  MM1((H)*4+0,(JH)*2+0,0); MM1((H)*4+0,(JH)*2+0,1); \
  MM1((H)*4+0,(JH)*2+1,0); MM1((H)*4+0,(JH)*2+1,1); \
  MM1((H)*4+1,(JH)*2+0,0); MM1((H)*4+1,(JH)*2+0,1); \
  MM1((H)*4+1,(JH)*2+1,0); MM1((H)*4+1,(JH)*2+1,1); \
  MM1((H)*4+2,(JH)*2+0,0); MM1((H)*4+2,(JH)*2+0,1); \
  MM1((H)*4+2,(JH)*2+1,0); MM1((H)*4+2,(JH)*2+1,1); \
  MM1((H)*4+3,(JH)*2+0,0); MM1((H)*4+3,(JH)*2+0,1); \
  MM1((H)*4+3,(JH)*2+1,0); MM1((H)*4+3,(JH)*2+1,1); } while (0)

__global__ __launch_bounds__(512, 2) void gemm8i_kernel(
    const signed char* __restrict__ Xq,      // [M][K] i8
    const signed char* __restrict__ Wq,      // [N][K] i8
    const float* __restrict__ xs,            // [M] per-row x scale
    const float* __restrict__ scale,         // [N]
    const float* __restrict__ bias,          // [N]
    float* __restrict__ C) {
  // lds[buf][0]=A tile [256][128] i8, lds[buf][1]=B tile; 128 KiB total
  __shared__ __attribute__((aligned(16))) signed char lds[2][2][256 * 128];

  const int tid = threadIdx.x;
  const int lane = tid & 63, wid = tid >> 6;
  const int wr = wid >> 2, wc = wid & 3;       // 2 x 4 wave grid, each 128x64 out
  const int rl = lane & 15, q = lane >> 4;

  // T1: bijective XCD swizzle (2048 blocks, %8 == 0)
  const int bid = blockIdx.x;
  const int swz = (bid & 7) * 256 + (bid >> 3);
  const long m0 = (long)(swz >> 6) * 256;
  const long n0 = (long)(swz & 63) * 256;

  // staging: thread t covers row sr, 16B granule (t&7), source pre-swizzled (rule 21)
  const int sr = tid >> 3;
  const int sgb = ((tid & 7) ^ (sr & 7)) * 16;  // byte offset within 128B row

  // read-side swizzle: byte ^= ((row&7)<<4)
  const int xm = (rl & 7) << 4;
  const int koff0 = (q * 16) ^ xm;              // ks=0 (k 0..63)
  const int koff1 = (64 + q * 16) ^ xm;         // ks=1 (k 64..127)

  i4v acc[8][4] = {};
  i4v aF[4][2], bF[4][2];

  // ---- prologue: tile0 full (8 quarters) + tile1 B + A-q0,q2 (6 quarters) ----
  STAGE_B(0, 0, 0); STAGE_B(0, 64, 0); STAGE_B(0, 128, 0); STAGE_B(0, 192, 0);
  STAGE_A(0, 0, 0); STAGE_A(0, 64, 0); STAGE_A(0, 128, 0); STAGE_A(0, 192, 0);
  STAGE_B(1, 0, 1); STAGE_B(1, 64, 1); STAGE_B(1, 128, 1); STAGE_B(1, 192, 1);
  STAGE_A(1, 0, 1); STAGE_A(1, 128, 1);
  VMCNT6;   // tile0's 8 landed; tile1's 6 in flight
  BAR;

  for (int it = 0; it < NIT; ++it) {
    const int t1 = 2 * it + 1, t2 = 2 * it + 2, t3 = 2 * it + 3;
    // ph0: compute tile 2it quadrant (0,0); stage t1 A-q1,q3 (read at ph6)
    LDA4(0, 0); LDB4(0);
    STAGE_A(1, 64, t1); STAGE_A(1, 192, t1);
    WAIT_LGKM; PRIO1; MM16(0, 0); PRIO0;
    BAR;
    // ph1: quadrant (0,1); stage t2 B-q0,q1 (B buf retired at ph0)
    STAGE_B(0, 0, t2); STAGE_B(0, 64, t2);
    PRIO1; MM16(0, 1); PRIO0;
    BAR;
    // ph2: quadrant (1,0); stage t2 B-q2,q3
    LDA4(0, 1);
    STAGE_B(0, 128, t2); STAGE_B(0, 192, t2);
    WAIT_LGKM; PRIO1; MM16(1, 0); PRIO0;
    BAR;
    // ph3: quadrant (1,1); stage t2 A-q0,q2; tile-boundary wait
    STAGE_A(0, 0, t2); STAGE_A(0, 128, t2);
    PRIO1; MM16(1, 1); PRIO0;
    if (it == NIT - 1) { VMCNT0; } else { VMCNT6; }   // t1 fully landed
    BAR;
    // ph4: tile 2it+1 quadrant (0,0); stage t2 A-q1,q3
    LDA4(1, 0); LDB4(1);
    STAGE_A(0, 64, t2); STAGE_A(0, 192, t2);
    WAIT_LGKM; PRIO1; MM16(0, 0); PRIO0;
    BAR;
    // ph5: quadrant (0,1); stage t3 B-q0,q1
    STAGE_B(1, 0, t3); STAGE_B(1, 64, t3);
    PRIO1; MM16(0, 1); PRIO0;
    BAR;
    // ph6: quadrant (1,0); stage t3 B-q2,q3
    LDA4(1, 1);
    STAGE_B(1, 128, t3); STAGE_B(1, 192, t3);
    WAIT_LGKM; PRIO1; MM16(1, 0); PRIO0;
    BAR;
    // ph7: quadrant (1,1); stage t3 A-q0,q2; boundary wait
    STAGE_A(1, 0, t3); STAGE_A(1, 128, t3);
    PRIO1; MM16(1, 1); PRIO0;
    VMCNT6;   // t2 fully landed for next iter's ph0
    BAR;
  }

  // ---- epilogue: y = acc * xs[row] * (1/scale[col]) + bias[col] ----
#pragma unroll
  for (int j = 0; j < 4; j++) {
    const long col = n0 + wc * 64 + j * 16 + rl;
    const float rs = 1.0f / scale[col];
    const float bv = bias[col];
#pragma unroll
    for (int i = 0; i < 8; i++) {
      const long row0 = m0 + wr * 128 + i * 16 + q * 4;
#pragma unroll
      for (int r = 0; r < 4; r++) {
        C[(row0 + r) * (long)FEATS + col] = (float)acc[i][j][r] * xs[row0 + r] * rs + bv;
      }
    }
  }
}

// ---------------- fallback (ws too small): naive fp32 tiled GEMM ----------------
__global__ void naive_kernel(const float* __restrict__ x, const int* __restrict__ kq,
                             const float* __restrict__ scale, const float* __restrict__ bias,
                             float* __restrict__ out) {
  __shared__ float xa[16][16];
  __shared__ float wb[16][17];
  const int n = blockIdx.x * 16 + threadIdx.x;
  const int m = blockIdx.y * 16 + threadIdx.y;
  float accv = 0.f;
  for (int k0 = 0; k0 < D_IN; k0 += 16) {
    xa[threadIdx.y][threadIdx.x] = x[(long)m * D_IN + k0 + threadIdx.x];
    wb[threadIdx.y][threadIdx.x] = (float)kq[(long)(k0 + threadIdx.y) * FEATS + n];
    __syncthreads();
#pragma unroll
    for (int kk = 0; kk < 16; kk++) accv += xa[threadIdx.y][kk] * wb[kk][threadIdx.x];
    __syncthreads();
  }
  out[(long)m * FEATS + n] = accv * (1.0f / scale[n]) + bias[n];
}

extern "C" void kernel_launch(void* const* d_in, const int* in_sizes, int n_in,
                              void* d_out, int out_size, void* d_ws, size_t ws_size,
                              hipStream_t stream) {
  const float* x     = (const float*)d_in[0];
  const int*   kq    = (const int*)d_in[1];
  const float* scale = (const float*)d_in[2];
  const float* bias  = (const float*)d_in[3];
  float* out = (float*)d_out;

  const size_t need = (size_t)TOKENS * D_IN + (size_t)FEATS * D_IN + TOKENS * 4;
  if (ws_size < need) {
    naive_kernel<<<dim3(FEATS / 16, TOKENS / 16), dim3(16, 16), 0, stream>>>(
        x, kq, scale, bias, out);
    return;
  }

  signed char* Xq = (signed char*)d_ws;
  signed char* Wq = Xq + (size_t)TOKENS * D_IN;
  float* xs = (float*)(Wq + (size_t)FEATS * D_IN);

  quant_x_kernel<<<TOKENS, 256, 0, stream>>>(x, Xq, xs);
  wtrans8_kernel<<<dim3(FEATS / 64, D_IN / 64), dim3(256), 0, stream>>>(kq, Wq);
  gemm8i_kernel<<<dim3((TOKENS / 256) * (FEATS / 256)), 512, 0, stream>>>(
      Xq, Wq, xs, scale, bias, out);
}